// Round 2
// baseline (583.627 us; speedup 1.0000x reference)
//
#include <hip/hip_runtime.h>

// out[n,:] = ci[n] * ( (Σ_{e: dst=n} ci[src_e]·mask_e · feat[e,:]) @ W^T )
// Pass 1 exploits linearity of the matmul over the segment-sum and the 70%
// zero-rate of the dropout mask: only ~30% of edges touch memory/atomics.
// Pass 2 is a tiny dense [N,64]x[64,64] row transform, done in-place in fp32.

// ---- Pass 1: g[dst[e],:] += (ci[src]*mask*ci[dst]) * feat[e,:]  (skip mask==0)
__global__ __launch_bounds__(256)
void gcn_scatter(const float* __restrict__ feat,  // [E,64]
                 const float* __restrict__ ci,    // [N]
                 const float* __restrict__ mask,  // [E]
                 const int*   __restrict__ src,
                 const int*   __restrict__ dst,
                 float* __restrict__ g,           // [N,64] pre-zeroed (= d_out)
                 int E)
{
    const int lane = threadIdx.x & 63;
    const int grp  = lane >> 4;    // 4 edges per wave, 16 lanes each
    const int l16  = lane & 15;
    const int wid  = (blockIdx.x * blockDim.x + threadIdx.x) >> 6;
    const int nw   = (gridDim.x * blockDim.x) >> 6;

    for (int base = wid * 4; base < E; base += nw * 4) {
        const int e = base + grp;
        float sv = 0.0f;
        int   db = 0;
        if (e < E) {
            const float m = mask[e];         // 0 for 70% of edges
            if (m != 0.0f) {
                const int is = src[e];
                const int id = dst[e];
                sv = ci[is] * m * ci[id];    // fold dst-node scale in here
                db = id * 64;
            }
        }
        if (sv != 0.0f) {                    // uniform per 16-lane group
            const float4 v = *(const float4*)(feat + (size_t)e * 64 + l16 * 4);
            float* p = g + db + l16 * 4;
            unsafeAtomicAdd(p + 0, v.x * sv);
            unsafeAtomicAdd(p + 1, v.y * sv);
            unsafeAtomicAdd(p + 2, v.z * sv);
            unsafeAtomicAdd(p + 3, v.w * sv);
        }
    }
}

// ---- Pass 2: g[n,:] = g[n,:] @ W^T  (in-place, fp32 exact)
// lane f holds W[f][0..63] in 64 VGPRs; g-row broadcast through LDS.
__global__ __launch_bounds__(256)
void gcn_rowgemm(const float* __restrict__ W,  // [64,64] row-major [f][k]
                 float* __restrict__ g,        // [N,64] in-out
                 int N)
{
    __shared__ float grow[4][64];
    const int lane = threadIdx.x & 63;
    const int wave = threadIdx.x >> 6;

    float w[64];
#pragma unroll
    for (int j = 0; j < 16; ++j) {
        const float4 t = *(const float4*)(W + lane * 64 + j * 4);
        w[j * 4 + 0] = t.x; w[j * 4 + 1] = t.y;
        w[j * 4 + 2] = t.z; w[j * 4 + 3] = t.w;
    }

    const int wid = blockIdx.x * 4 + wave;
    const int nw  = gridDim.x * 4;
    for (int n = wid; n < N; n += nw) {
        const float gv = g[(size_t)n * 64 + lane];
        grow[wave][lane] = gv;               // same-wave ds ordering, no barrier
        float acc = 0.0f;
#pragma unroll
        for (int k = 0; k < 64; ++k)
            acc = fmaf(grow[wave][k], w[k], acc);   // LDS broadcast read
        g[(size_t)n * 64 + lane] = acc;      // row fully read before store
    }
}

extern "C" void kernel_launch(void* const* d_in, const int* in_sizes, int n_in,
                              void* d_out, int out_size, void* d_ws, size_t ws_size,
                              hipStream_t stream) {
    const float* feat = (const float*)d_in[0];
    const float* ci   = (const float*)d_in[1];
    const float* W    = (const float*)d_in[2];
    const float* mask = (const float*)d_in[3];
    const int*   src  = (const int*)d_in[4];
    const int*   dst  = (const int*)d_in[5];
    float* out = (float*)d_out;

    const int E = in_sizes[3];   // drop_mask is [E]
    const int N = in_sizes[1];   // ci is [N]

    hipMemsetAsync(d_out, 0, (size_t)out_size * sizeof(float), stream);

    gcn_scatter<<<dim3(2048), dim3(256), 0, stream>>>(feat, ci, mask, src, dst, out, E);
    gcn_rowgemm<<<dim3(1024), dim3(256), 0, stream>>>(W, out, N);
}

// Round 3
// 481.283 us; speedup vs baseline: 1.2126x; 1.2126x over previous
//
#include <hip/hip_runtime.h>

// out[n,:] = ci[n] * ( (Σ_{e: dst=n} ci[src_e]·mask_e · feat[e,:]) @ W^T )
// Pass 1: scatter scaled raw features (linearity moves the matmul after the
// segment-sum). 70% of edges have mask==0 and are skipped entirely.
// CRITICAL layout fact (R1 vs R2 counters): f32 atomics write through L2 at
// 16B sector granularity and only combine within a sector. Lane l16 must
// cover floats {i*16 + l16} so each atomic instruction is 64B-contiguous
// per 16-lane group -> 4 atomics per sector -> 4x less write-through traffic.
// Pass 2: tiny [N,64]x[64,64] fp32 row transform, LDS-broadcast b128 reads.

// ---- Pass 1: g[dst[e],:] += (ci[src]*mask*ci[dst]) * feat[e,:]
__global__ __launch_bounds__(256)
void gcn_scatter(const float* __restrict__ feat,  // [E,64]
                 const float* __restrict__ ci,    // [N]
                 const float* __restrict__ mask,  // [E]
                 const int*   __restrict__ src,
                 const int*   __restrict__ dst,
                 float* __restrict__ g,           // [N,64] pre-zeroed (= d_out)
                 int E)
{
    const int lane = threadIdx.x & 63;
    const int grp  = lane >> 4;    // 4 edges per wave, 16 lanes each
    const int l16  = lane & 15;
    const int wid  = (blockIdx.x * blockDim.x + threadIdx.x) >> 6;
    const int nw   = (gridDim.x * blockDim.x) >> 6;

    for (int base = wid * 4; base < E; base += nw * 4) {
        const int e = base + grp;
        float sv = 0.0f;
        int   db = 0;
        if (e < E) {
            const float m = mask[e];             // 0 for 70% of edges
            if (m != 0.0f) {
                const int is = src[e];
                const int id = dst[e];
                sv = ci[is] * m * ci[id];        // fold dst-node scale in
                db = id * 64;
            }
        }
        if (sv != 0.0f) {
            const float* fr = feat + (size_t)e * 64;
#pragma unroll
            for (int i = 0; i < 4; ++i) {
                // atomic i: group covers floats [i*16, i*16+16) -> 64B contiguous
                const float v = fr[i * 16 + l16];
                unsafeAtomicAdd(g + db + i * 16 + l16, v * sv);
            }
        }
    }
}

// ---- Pass 2: g[n,:] = g[n,:] @ W^T  (in-place, fp32 exact)
// lane f holds W[f][0..63] in 64 VGPRs; 4 rows per wave-iter for ILP;
// g-row k-values broadcast to all lanes via ds_read_b128 (same-address).
__global__ __launch_bounds__(256)
void gcn_rowgemm(const float* __restrict__ W,  // [64,64] row-major [f][k]
                 float* __restrict__ g,        // [N,64] in-out
                 int N)
{
    __shared__ float grow[4][4][64];           // [wave][row][k]
    const int lane = threadIdx.x & 63;
    const int wave = threadIdx.x >> 6;

    float w[64];
#pragma unroll
    for (int j = 0; j < 16; ++j) {
        const float4 t = *(const float4*)(W + lane * 64 + j * 4);
        w[j * 4 + 0] = t.x; w[j * 4 + 1] = t.y;
        w[j * 4 + 2] = t.z; w[j * 4 + 3] = t.w;
    }

    const int wid = blockIdx.x * 4 + wave;
    const int nw  = gridDim.x * 4;
    for (int n0 = wid * 4; n0 < N; n0 += nw * 4) {
#pragma unroll
        for (int r = 0; r < 4; ++r)
            if (n0 + r < N)
                grow[wave][r][lane] = g[(size_t)(n0 + r) * 64 + lane];
        // same-wave LDS write->read ordering: compiler inserts lgkmcnt wait

        float acc[4] = {0.f, 0.f, 0.f, 0.f};
#pragma unroll
        for (int k4 = 0; k4 < 16; ++k4) {
#pragma unroll
            for (int r = 0; r < 4; ++r) {
                const float4 a = *(const float4*)(&grow[wave][r][k4 * 4]);
                acc[r] = fmaf(a.x, w[k4 * 4 + 0], acc[r]);
                acc[r] = fmaf(a.y, w[k4 * 4 + 1], acc[r]);
                acc[r] = fmaf(a.z, w[k4 * 4 + 2], acc[r]);
                acc[r] = fmaf(a.w, w[k4 * 4 + 3], acc[r]);
            }
        }
#pragma unroll
        for (int r = 0; r < 4; ++r)
            if (n0 + r < N)
                g[(size_t)(n0 + r) * 64 + lane] = acc[r];
    }
}

extern "C" void kernel_launch(void* const* d_in, const int* in_sizes, int n_in,
                              void* d_out, int out_size, void* d_ws, size_t ws_size,
                              hipStream_t stream) {
    const float* feat = (const float*)d_in[0];
    const float* ci   = (const float*)d_in[1];
    const float* W    = (const float*)d_in[2];
    const float* mask = (const float*)d_in[3];
    const int*   src  = (const int*)d_in[4];
    const int*   dst  = (const int*)d_in[5];
    float* out = (float*)d_out;

    const int E = in_sizes[3];   // drop_mask is [E]
    const int N = in_sizes[1];   // ci is [N]

    hipMemsetAsync(d_out, 0, (size_t)out_size * sizeof(float), stream);

    gcn_scatter<<<dim3(2048), dim3(256), 0, stream>>>(feat, ci, mask, src, dst, out, E);
    gcn_rowgemm<<<dim3(512), dim3(256), 0, stream>>>(W, out, N);
}

// Round 4
// 375.713 us; speedup vs baseline: 1.5534x; 1.2810x over previous
//
#include <hip/hip_runtime.h>

// out[n,:] = ci[n] * ( (Σ_{e: dst=n} ci[src_e]·mask_e · feat[e,:]) @ W^T )
// Pass 1 (scatter): linearity moves the matmul after the segment-sum; 70% of
//   edges have mask==0 and are skipped. Ballot-compaction: dense coalesced
//   meta loads for 64 edges/wave, then full-wave 256B feat row + 256B atomic
//   per surviving edge, software-pipelined in pairs.
//   HW model (R1/R2 counters): f32 atomics write through L2 at 16B sector
//   granularity, combining within a sector, at ~71G sectors/s device-wide.
//   300K surviving rows x 16 sectors = 4.8M sectors -> ~68us floor.
// Pass 2 (rowgemm): [N,64]x[64,64]^T via bf16 MFMA 16x16x32, W-frags in
//   registers, A-frags straight from global in MFMA layout (R1-verified).

typedef __attribute__((ext_vector_type(8))) short bf16x8;
typedef __attribute__((ext_vector_type(4))) float f32x4;

static __device__ __forceinline__ short f2bf(float f) {
    union { float f; unsigned u; } v; v.f = f;
    unsigned r = v.u + 0x7FFFu + ((v.u >> 16) & 1u);
    return (short)(r >> 16);
}

// ---- Pass 1: g[dst[e],:] += (ci[src]*mask*ci[dst]) * feat[e,:]
__global__ __launch_bounds__(256)
void gcn_scatter(const float* __restrict__ feat,  // [E,64]
                 const float* __restrict__ ci,    // [N]
                 const float* __restrict__ mask,  // [E]
                 const int*   __restrict__ src,
                 const int*   __restrict__ dst,
                 float* __restrict__ g,           // [N,64] pre-zeroed (= d_out)
                 int E)
{
    const int lane = threadIdx.x & 63;
    const int wid  = (blockIdx.x * blockDim.x + threadIdx.x) >> 6;
    const int nw   = (gridDim.x * blockDim.x) >> 6;

    for (int base = wid * 64; base < E; base += nw * 64) {
        // dense, fully-coalesced meta for 64 edges; gathers gated on mask!=0
        const int e = base + lane;
        float sv = 0.0f;
        int   db = 0;
        if (e < E) {
            const float m = mask[e];             // 0 for 70% of edges
            if (m != 0.0f) {
                const int id = dst[e];
                sv = ci[src[e]] * m * ci[id];    // fold dst-node scale in
                db = id * 64;
            }
        }
        unsigned long long alive = __ballot(sv != 0.0f);

        // survivors in pairs: both feat loads issue before either vmcnt wait
        while (alive) {
            const int j0 = __builtin_ctzll(alive);
            alive &= alive - 1;
            int j1 = -1;
            if (alive) { j1 = __builtin_ctzll(alive); alive &= alive - 1; }

            const float s0 = __shfl(sv, j0, 64);
            const int   b0 = __shfl(db, j0, 64);
            const float v0 = feat[(size_t)(base + j0) * 64 + lane];

            float s1 = 0.0f; int b1 = 0; float v1 = 0.0f;
            if (j1 >= 0) {
                s1 = __shfl(sv, j1, 64);
                b1 = __shfl(db, j1, 64);
                v1 = feat[(size_t)(base + j1) * 64 + lane];
            }

            unsafeAtomicAdd(g + b0 + lane, v0 * s0);
            if (j1 >= 0)
                unsafeAtomicAdd(g + b1 + lane, v1 * s1);
        }
    }
}

// ---- Pass 2: g[n,:] = g[n,:] @ W^T  (in-place, bf16 MFMA)
__global__ __launch_bounds__(256)
void gcn_rowgemm(const float* __restrict__ W,  // [64,64] row-major [f][k]
                 float* __restrict__ g,        // [N,64] in-out
                 int N)
{
    const int lane = threadIdx.x & 63;
    const int wave = threadIdx.x >> 6;
    const int r16  = lane & 15;
    const int q    = lane >> 4;

    // B-frags: B[k][f] = W[f][k]; lane holds f = t*16+r16, k = s*32+q*8+j
    bf16x8 bfrag[4][2];
#pragma unroll
    for (int t = 0; t < 4; ++t) {
        const float* wrow = W + (t * 16 + r16) * 64;
#pragma unroll
        for (int s = 0; s < 2; ++s) {
            const float4 w0 = *(const float4*)(wrow + s * 32 + q * 8);
            const float4 w1 = *(const float4*)(wrow + s * 32 + q * 8 + 4);
            bf16x8 b;
            b[0] = f2bf(w0.x); b[1] = f2bf(w0.y); b[2] = f2bf(w0.z); b[3] = f2bf(w0.w);
            b[4] = f2bf(w1.x); b[5] = f2bf(w1.y); b[6] = f2bf(w1.z); b[7] = f2bf(w1.w);
            bfrag[t][s] = b;
        }
    }

    const int wid = blockIdx.x * 4 + wave;
    const int nw  = gridDim.x * 4;
    for (int n0 = wid * 16; n0 < N; n0 += nw * 16) {
        int ar = n0 + r16;                       // A row (N%16==0; clamp anyway)
        if (ar >= N) ar = N - 1;
        const float* arow = g + (size_t)ar * 64 + q * 8;
        bf16x8 afrag[2];
#pragma unroll
        for (int s = 0; s < 2; ++s) {
            const float4 a0 = *(const float4*)(arow + s * 32);
            const float4 a1 = *(const float4*)(arow + s * 32 + 4);
            bf16x8 a;
            a[0] = f2bf(a0.x); a[1] = f2bf(a0.y); a[2] = f2bf(a0.z); a[3] = f2bf(a0.w);
            a[4] = f2bf(a1.x); a[5] = f2bf(a1.y); a[6] = f2bf(a1.z); a[7] = f2bf(a1.w);
            afrag[s] = a;
        }

        f32x4 acc[4];
#pragma unroll
        for (int t = 0; t < 4; ++t) {
            f32x4 c = {0.f, 0.f, 0.f, 0.f};
            c = __builtin_amdgcn_mfma_f32_16x16x32_bf16(afrag[0], bfrag[t][0], c, 0, 0, 0);
            c = __builtin_amdgcn_mfma_f32_16x16x32_bf16(afrag[1], bfrag[t][1], c, 0, 0, 0);
            acc[t] = c;
        }

        // C layout (R1-verified): row = q*4 + r, col = t*16 + r16.
        // All A reads of this tile complete before stores (data dep); tiles
        // are wave-disjoint, so in-place is safe.
#pragma unroll
        for (int r = 0; r < 4; ++r) {
            const int orow = n0 + q * 4 + r;
            if (orow < N) {
#pragma unroll
                for (int t = 0; t < 4; ++t)
                    g[(size_t)orow * 64 + t * 16 + r16] = acc[t][r];
            }
        }
    }
}

extern "C" void kernel_launch(void* const* d_in, const int* in_sizes, int n_in,
                              void* d_out, int out_size, void* d_ws, size_t ws_size,
                              hipStream_t stream) {
    const float* feat = (const float*)d_in[0];
    const float* ci   = (const float*)d_in[1];
    const float* W    = (const float*)d_in[2];
    const float* mask = (const float*)d_in[3];
    const int*   src  = (const int*)d_in[4];
    const int*   dst  = (const int*)d_in[5];
    float* out = (float*)d_out;

    const int E = in_sizes[3];   // drop_mask is [E]
    const int N = in_sizes[1];   // ci is [N]

    hipMemsetAsync(d_out, 0, (size_t)out_size * sizeof(float), stream);

    gcn_scatter<<<dim3(2048), dim3(256), 0, stream>>>(feat, ci, mask, src, dst, out, E);
    gcn_rowgemm<<<dim3(1024), dim3(256), 0, stream>>>(W, out, N);
}